// Round 6
// baseline (2180.755 us; speedup 1.0000x reference)
//
#include <hip/hip_runtime.h>

#define E_CNT 80000
#define N_NODES 10000

typedef __attribute__((ext_vector_type(8))) __bf16 bf16x8;
typedef __attribute__((ext_vector_type(4))) float f32x4;

__device__ __forceinline__ float sigmoidf_(float x) { return 1.f / (1.f + __expf(-x)); }

__device__ __forceinline__ unsigned fkey(float f) {
  unsigned u = __float_as_uint(f);
  return (u & 0x80000000u) ? ~u : (u | 0x80000000u);
}
__device__ __forceinline__ float unfkey(unsigned k) {
  unsigned u = (k & 0x80000000u) ? (k & 0x7FFFFFFFu) : ~k;
  return __uint_as_float(u);
}

// ---------------------------------------------------------------------------
// Generic f32 [K, ld] (first N cols) -> bf16 MFMA-B fragment layout:
// dst[(ksg*N + col)*8 + j] = src[(ksg*8 + j)*ld + col],  ksg = 0..K/8-1.
// ---------------------------------------------------------------------------
__global__ __launch_bounds__(256) void k_cvt(const float* __restrict__ src,
                                             __bf16* __restrict__ dst,
                                             int K8, int N, int ld) {
  int idx = blockIdx.x * 256 + threadIdx.x;
  if (idx >= K8 * N) return;
  int ksg = idx / N, col = idx % N;
#pragma unroll
  for (int j = 0; j < 8; ++j)
    dst[(size_t)idx * 8 + j] = (__bf16)src[(size_t)(ksg * 8 + j) * ld + col];
}

// ---------------------------------------------------------------------------
// Phase 1 (R5 verbatim). 16 edges/block, 256 threads, 3 blocks/CU.
// ---------------------------------------------------------------------------
__global__ __launch_bounds__(256, 3) void k_phase1(
    const float* __restrict__ x, const int* __restrict__ an,
    const float* __restrict__ edist, const int* __restrict__ eidx,
    const float* __restrict__ wigner,
    const float* __restrict__ semb, const float* __restrict__ temb,
    const float* __restrict__ rw1, const float* __restrict__ rb1,
    const float* __restrict__ rlnw, const float* __restrict__ rlnb,
    const float* __restrict__ rw2, const float* __restrict__ rb2,
    const __bf16* __restrict__ w0r, const float* __restrict__ b0,
    const float* __restrict__ lnaw, const float* __restrict__ lnab,
    const float* __restrict__ adot,
    float* __restrict__ ws_attn, float* __restrict__ ws_apre)
{
  __shared__ __align__(16) float pool[6160];
  __shared__ __align__(16) float sb[2048];
  __shared__ __align__(16) __bf16 a_lds[6144];   // [ksg=48][e=16][j=8]
  __shared__ float wgs[432];
  __shared__ int sidx[16], tidx[16], ansh[16], anth[16];

  const int tid = threadIdx.x;
  const int e0 = blockIdx.x * 16;

  if (tid < 16) {
    int s = eidx[e0 + tid], t = eidx[E_CNT + e0 + tid];
    sidx[tid] = s; tidx[tid] = t; ansh[tid] = an[s]; anth[tid] = an[t];
  }
  for (int i = tid; i < 432; i += 256) {
    int e = i / 27, r = i % 27, kk = r / 9, j = r % 9;
    int row = (kk == 0) ? 0 : (kk == 1 ? 2 : 6);
    wgs[i] = wigner[(size_t)(e0 + e) * 81 + row * 9 + j];
  }
  __syncthreads();

  float* xe = pool;
  for (int i = tid; i < 16 * 320; i += 256) {
    int e = i / 320, c = i % 320;
    float v;
    if (c < 64)       v = edist[(size_t)(e0 + e) * 64 + c];
    else if (c < 192) v = semb[ansh[e] * 128 + (c - 64)];
    else              v = temb[anth[e] * 128 + (c - 192)];
    xe[e * 320 + c] = v;
  }
  __syncthreads();

  {
    int col = tid & 127, half = tid >> 7;
    float acc[8];
#pragma unroll
    for (int i = 0; i < 8; ++i) acc[i] = 0.f;
#pragma unroll 4
    for (int k = 0; k < 320; ++k) {
      float w = rw1[k * 128 + col];
#pragma unroll
      for (int i = 0; i < 8; ++i) acc[i] += xe[(half * 8 + i) * 320 + k] * w;
    }
    float bb = rb1[col];
#pragma unroll
    for (int i = 0; i < 8; ++i) sb[(half * 8 + i) * 128 + col] = acc[i] + bb;
  }
  __syncthreads();

  {
    int wid = tid >> 6, lane = tid & 63;
    for (int e = wid; e < 16; e += 4) {
      float v0 = sb[e * 128 + lane], v1 = sb[e * 128 + lane + 64];
      float s1 = v0 + v1, s2 = v0 * v0 + v1 * v1;
#pragma unroll
      for (int m = 32; m >= 1; m >>= 1) {
        s1 += __shfl_xor(s1, m);
        s2 += __shfl_xor(s2, m);
      }
      float mu = s1 * (1.f / 128.f);
      float var = s2 * (1.f / 128.f) - mu * mu;
      float rstd = rsqrtf(var + 1e-5f);
      float y0 = (v0 - mu) * rstd * rlnw[lane] + rlnb[lane];
      float y1 = (v1 - mu) * rstd * rlnw[lane + 64] + rlnb[lane + 64];
      sb[e * 128 + lane]      = y0 * sigmoidf_(y0) * (1.f / 0.6f);
      sb[e * 128 + lane + 64] = y1 * sigmoidf_(y1) * (1.f / 0.6f);
    }
  }
  __syncthreads();

  float* rbuf = pool;
  {
    int col128 = tid & 127, half = tid >> 7;
    for (int cc = 0; cc < 3; ++cc) {
      int col = cc * 128 + col128;
      float acc[8];
#pragma unroll
      for (int i = 0; i < 8; ++i) acc[i] = 0.f;
#pragma unroll 4
      for (int k = 0; k < 128; ++k) {
        float w = rw2[k * 768 + col];
#pragma unroll
        for (int i = 0; i < 8; ++i) acc[i] += sb[(half * 8 + i) * 128 + k] * w;
      }
      float bb = rb2[col];
#pragma unroll
      for (int i = 0; i < 8; ++i) rbuf[(half * 8 + i) * 385 + col] = acc[i] + bb;
    }
  }
  __syncthreads();

  {
    int e = tid & 15, cg = tid >> 4;
    int c0 = cg * 8;
    const float* xb = (c0 < 64) ? (x + (size_t)sidx[e] * 576 + c0)
                                : (x + (size_t)tidx[e] * 576 + (c0 - 64));
    float xc[9][8];
#pragma unroll
    for (int j = 0; j < 9; ++j) {
      float4 u0 = *(const float4*)(xb + j * 64);
      float4 u1 = *(const float4*)(xb + j * 64 + 4);
      xc[j][0] = u0.x; xc[j][1] = u0.y; xc[j][2] = u0.z; xc[j][3] = u0.w;
      xc[j][4] = u1.x; xc[j][5] = u1.y; xc[j][6] = u1.z; xc[j][7] = u1.w;
    }
#pragma unroll
    for (int kk = 0; kk < 3; ++kk) {
      float wv[9];
#pragma unroll
      for (int j = 0; j < 9; ++j) wv[j] = wgs[e * 27 + kk * 9 + j];
      __bf16* ap = a_lds + ((kk * 16 + cg) * 16 + e) * 8;
#pragma unroll
      for (int cu = 0; cu < 8; ++cu) {
        float m = 0.f;
#pragma unroll
        for (int j = 0; j < 9; ++j) m += wv[j] * xc[j][cu];
        int colc = kk * 128 + c0 + cu;
        ap[cu] = (__bf16)(m * rbuf[e * 385 + colc]);
      }
    }
  }
  __syncthreads();

  float* sb5 = pool;
  {
    int lane = tid & 63, wv = tid >> 6;
    int erow = lane & 15, g = lane >> 4;
    bf16x8 af[12];
#pragma unroll
    for (int ks = 0; ks < 12; ++ks)
      af[ks] = *(const bf16x8*)(a_lds + ((ks * 4 + g) * 16 + erow) * 8);
    for (int tt = 0; tt < 9; ++tt) {
      int tile = wv * 9 + tt;
      int col = tile * 16 + erow;
      f32x4 acc = {0.f, 0.f, 0.f, 0.f};
#pragma unroll
      for (int ks = 0; ks < 12; ++ks) {
        bf16x8 bf = *(const bf16x8*)(w0r + ((size_t)((ks * 4 + g) * 576) + col) * 8);
        acc = __builtin_amdgcn_mfma_f32_16x16x32_bf16(af[ks], bf, acc, 0, 0, 0);
      }
      if (tile < 16) {
#pragma unroll
        for (int r = 0; r < 4; ++r) sb5[(g * 4 + r) * 260 + col] = acc[r];
      } else {
        float bb = b0[col];
#pragma unroll
        for (int r = 0; r < 4; ++r)
          ws_attn[(size_t)(e0 + g * 4 + r) * 320 + (col - 256)] = acc[r] + bb;
      }
    }
  }
  __syncthreads();

  {
    float bb = b0[tid];
    int h = tid >> 5, kk = tid & 31;
    float lw = lnaw[kk], lb = lnab[kk], ad = adot[h * 32 + kk];
#pragma unroll
    for (int e = 0; e < 16; ++e) {
      float v = sb5[e * 260 + tid] + bb;
      float s1 = v, s2 = v * v;
#pragma unroll
      for (int m = 16; m >= 1; m >>= 1) {
        s1 += __shfl_xor(s1, m);
        s2 += __shfl_xor(s2, m);
      }
      float mu = s1 * (1.f / 32.f);
      float var = s2 * (1.f / 32.f) - mu * mu;
      float rstd = rsqrtf(var + 1e-5f);
      float xn = (v - mu) * rstd * lw + lb;
      float sl = 0.6f * xn + 0.4f * xn * (2.f * sigmoidf_(xn) - 1.f);
      float p = sl * ad;
#pragma unroll
      for (int m = 16; m >= 1; m >>= 1) p += __shfl_xor(p, m);
      if (kk == 0) ws_apre[(size_t)(e0 + e) * 8 + h] = p;
    }
  }
}

// ---------------------------------------------------------------------------
// segment max / exp-sum
// ---------------------------------------------------------------------------
__global__ __launch_bounds__(256) void k_segmax(const float* __restrict__ apre,
                                                const int* __restrict__ eidx,
                                                unsigned* __restrict__ segk) {
  int idx = blockIdx.x * 256 + threadIdx.x;
  if (idx >= E_CNT * 8) return;
  int e = idx >> 3, h = idx & 7;
  int t = eidx[E_CNT + e];
  atomicMax(&segk[t * 8 + h], fkey(apre[idx]));
}

__global__ __launch_bounds__(256) void k_expsum(const float* __restrict__ apre,
                                                const int* __restrict__ eidx,
                                                const unsigned* __restrict__ segk,
                                                float* __restrict__ ex_out,
                                                float* __restrict__ denom) {
  int idx = blockIdx.x * 256 + threadIdx.x;
  if (idx >= E_CNT * 8) return;
  int e = idx >> 3, h = idx & 7;
  int t = eidx[E_CNT + e];
  float m = unfkey(segk[t * 8 + h]);
  float ex = __expf(apre[idx] - m);
  ex_out[idx] = ex;
  atomicAdd(&denom[t * 8 + h], ex);
}

// ---------------------------------------------------------------------------
// Phase 2: gates (f32 VALU) -> msg in bf16 A-frag layout -> so2_conv2 via
// MFMA -> alpha*wigner_inv epilogue + atomic scatter.  16 edges/block.
// ---------------------------------------------------------------------------
__global__ __launch_bounds__(256, 2) void k_phase2(
    const float* __restrict__ x, const int* __restrict__ eidx,
    const float* __restrict__ t_ij, const float* __restrict__ rl_ij,
    const float* __restrict__ winv,
    const float* __restrict__ gwh, const float* __restrict__ gwx, const float* __restrict__ gwt,
    const __bf16* __restrict__ w0b, const float* __restrict__ b0,
    const __bf16* __restrict__ w1b, const __bf16* __restrict__ w2b,
    const float* __restrict__ ws_attn, const float* __restrict__ ws_ex,
    const float* __restrict__ denom,
    float* __restrict__ node)
{
  __shared__ __align__(16) float xs[16 * 576];
  __shared__ __align__(16) __bf16 mb[9 * 8 * 16 * 8];   // [row][ksg][e][j]
  __shared__ float wib[16 * 81];
  __shared__ float alp[16 * 8];
  __shared__ float rlb[16 * 8];
  __shared__ float malp[16];
  __shared__ int tnode[16];

  const int tid = threadIdx.x;
  const int e0 = blockIdx.x * 16;

  if (tid < 16) tnode[tid] = eidx[E_CNT + e0 + tid];
  __syncthreads();

  if (tid < 128) {
    int e = tid >> 3, h = tid & 7;
    float ex = ws_ex[(size_t)(e0 + e) * 8 + h];
    alp[tid] = ex / (denom[tnode[e] * 8 + h] + 1e-16f);
  } else {
    int i = tid - 128;
    int e = i >> 3;
    rlb[i] = rl_ij[(size_t)(e0 + e) * 8 + (i & 7)];
  }
  for (int i = tid; i < 16 * 81; i += 256) {
    int e = i / 81, r = i % 81;
    wib[i] = winv[(size_t)(e0 + e) * 81 + r];
  }
  for (int i = tid; i < 16 * 576; i += 256) {
    int e = i / 576, c = i % 576;
    xs[i] = x[(size_t)tnode[e] * 576 + c];
  }
  __syncthreads();
  if (tid < 16) {
    float s = 0.f;
#pragma unroll
    for (int h = 0; h < 8; ++h) s += alp[tid * 8 + h];
    malp[tid] = s * 0.125f;
  }
  __syncthreads();

  // gates: f32 VALU; results written as bf16 into mb (A-fragment layout)
  {
    int d = tid & 63, wid = tid >> 6;
    float acch[4] = {0.f, 0.f, 0.f, 0.f}, acct[4] = {0.f, 0.f, 0.f, 0.f};
#pragma unroll 4
    for (int k = 0; k < 64; ++k) {
      float w = gwh[k * 64 + d];
#pragma unroll
      for (int i = 0; i < 4; ++i) acch[i] += xs[(wid * 4 + i) * 576 + k] * w;
    }
#pragma unroll 4
    for (int k = 0; k < 128; ++k) {
      float w = gwt[k * 64 + d];
#pragma unroll
      for (int i = 0; i < 4; ++i) acct[i] += t_ij[(size_t)(e0 + wid * 4 + i) * 128 + k] * w;
    }
    float xp[4][8];
#pragma unroll
    for (int i = 0; i < 4; ++i)
#pragma unroll
      for (int k8 = 0; k8 < 8; ++k8) xp[i][k8] = 0.f;
#pragma unroll 2
    for (int c = 0; c < 64; ++c) {
      float w = gwx[c * 64 + d];
#pragma unroll
      for (int i = 0; i < 4; ++i) {
#pragma unroll
        for (int k8 = 0; k8 < 8; ++k8)
          xp[i][k8] += xs[(wid * 4 + i) * 576 + (k8 + 1) * 64 + c] * w;
      }
    }
    const int dk = d >> 3, dj = d & 7;
#pragma unroll
    for (int i = 0; i < 4; ++i) {
      int e = wid * 4 + i;
      float ml = malp[e];
      const float* wsb = ws_attn + (size_t)(e0 + e) * 320;
      float hv = acch[i]; hv = hv * sigmoidf_(hv);
      float tv = acct[i]; tv = tv * sigmoidf_(tv);
      float os  = wsb[d] * ml;
      float od0 = wsb[64 + d] * ml,  od1 = wsb[128 + d] * ml;
      float ot0 = wsb[192 + d] * ml, ot1 = wsb[256 + d] * ml;
      mb[((0 * 8 + dk) * 16 + e) * 8 + dj] = (__bf16)(os * hv);
#pragma unroll
      for (int j = 0; j < 3; ++j)
        mb[(((1 + j) * 8 + dk) * 16 + e) * 8 + dj] =
            (__bf16)(od0 * xp[i][j] + ot0 * tv * rlb[e * 8 + j]);
#pragma unroll
      for (int j = 0; j < 5; ++j)
        mb[(((4 + j) * 8 + dk) * 16 + e) * 8 + dj] =
            (__bf16)(od1 * xp[i][3 + j] + ot1 * tv * rlb[e * 8 + 3 + j]);
    }
  }
  __syncthreads();

  // so2_conv2 via MFMA. Wave wv handles channel groups wv*2, wv*2+1.
  {
    const int lane = tid & 63, wv = tid >> 6;
    const int e16 = lane & 15, g = lane >> 4;
#define AF(row, ksg) (*(const bf16x8*)(mb + (((row) * 8 + (ksg)) * 16 + e16) * 8))
#pragma unroll 1
    for (int gi = 0; gi < 2; ++gi) {
      const int c = (wv * 2 + gi) * 16 + e16;   // channel 0..127
      float m2[9][4];
      {  // wm1: y0 = rows(3,7)@W1, y1 = rows(1,5)@W1 ; K=128, N=512
        f32x4 y0a[4], y1a[4];
#pragma unroll
        for (int q = 0; q < 4; ++q) {
          y0a[q] = (f32x4){0.f, 0.f, 0.f, 0.f};
          y1a[q] = (f32x4){0.f, 0.f, 0.f, 0.f};
        }
        bf16x8 a30 = AF(3, g), a31 = AF(3, 4 + g), a70 = AF(7, g), a71 = AF(7, 4 + g);
        bf16x8 a10 = AF(1, g), a11 = AF(1, 4 + g), a50 = AF(5, g), a51 = AF(5, 4 + g);
#pragma unroll
        for (int q = 0; q < 4; ++q) {
          int col = c + q * 128;
          bf16x8 wf0 = *(const bf16x8*)(w1b + ((size_t)((0 * 4 + g) * 512 + col)) * 8);
          bf16x8 wf1 = *(const bf16x8*)(w1b + ((size_t)((1 * 4 + g) * 512 + col)) * 8);
          bf16x8 wf2 = *(const bf16x8*)(w1b + ((size_t)((2 * 4 + g) * 512 + col)) * 8);
          bf16x8 wf3 = *(const bf16x8*)(w1b + ((size_t)((3 * 4 + g) * 512 + col)) * 8);
          y0a[q] = __builtin_amdgcn_mfma_f32_16x16x32_bf16(a30, wf0, y0a[q], 0, 0, 0);
          y0a[q] = __builtin_amdgcn_mfma_f32_16x16x32_bf16(a31, wf1, y0a[q], 0, 0, 0);
          y0a[q] = __builtin_amdgcn_mfma_f32_16x16x32_bf16(a70, wf2, y0a[q], 0, 0, 0);
          y0a[q] = __builtin_amdgcn_mfma_f32_16x16x32_bf16(a71, wf3, y0a[q], 0, 0, 0);
          y1a[q] = __builtin_amdgcn_mfma_f32_16x16x32_bf16(a10, wf0, y1a[q], 0, 0, 0);
          y1a[q] = __builtin_amdgcn_mfma_f32_16x16x32_bf16(a11, wf1, y1a[q], 0, 0, 0);
          y1a[q] = __builtin_amdgcn_mfma_f32_16x16x32_bf16(a50, wf2, y1a[q], 0, 0, 0);
          y1a[q] = __builtin_amdgcn_mfma_f32_16x16x32_bf16(a51, wf3, y1a[q], 0, 0, 0);
        }
#pragma unroll
        for (int r = 0; r < 4; ++r) {
          m2[3][r] = y0a[0][r] - y1a[2][r];
          m2[7][r] = y0a[1][r] - y1a[3][r];
          m2[1][r] = y1a[0][r] + y0a[2][r];
          m2[5][r] = y1a[1][r] + y0a[3][r];
        }
      }
      {  // wm0: rows(0,2,6)@W0 + bias ; K=192, N=384
        f32x4 aq[3];
#pragma unroll
        for (int q = 0; q < 3; ++q) aq[q] = (f32x4){0.f, 0.f, 0.f, 0.f};
        bf16x8 a00 = AF(0, g), a01 = AF(0, 4 + g);
        bf16x8 a20 = AF(2, g), a21 = AF(2, 4 + g);
        bf16x8 a60 = AF(6, g), a61 = AF(6, 4 + g);
#pragma unroll
        for (int q = 0; q < 3; ++q) {
          int col = c + q * 128;
          bf16x8 wf0 = *(const bf16x8*)(w0b + ((size_t)((0 * 4 + g) * 384 + col)) * 8);
          bf16x8 wf1 = *(const bf16x8*)(w0b + ((size_t)((1 * 4 + g) * 384 + col)) * 8);
          bf16x8 wf2 = *(const bf16x8*)(w0b + ((size_t)((2 * 4 + g) * 384 + col)) * 8);
          bf16x8 wf3 = *(const bf16x8*)(w0b + ((size_t)((3 * 4 + g) * 384 + col)) * 8);
          bf16x8 wf4 = *(const bf16x8*)(w0b + ((size_t)((4 * 4 + g) * 384 + col)) * 8);
          bf16x8 wf5 = *(const bf16x8*)(w0b + ((size_t)((5 * 4 + g) * 384 + col)) * 8);
          aq[q] = __builtin_amdgcn_mfma_f32_16x16x32_bf16(a00, wf0, aq[q], 0, 0, 0);
          aq[q] = __builtin_amdgcn_mfma_f32_16x16x32_bf16(a01, wf1, aq[q], 0, 0, 0);
          aq[q] = __builtin_amdgcn_mfma_f32_16x16x32_bf16(a20, wf2, aq[q], 0, 0, 0);
          aq[q] = __builtin_amdgcn_mfma_f32_16x16x32_bf16(a21, wf3, aq[q], 0, 0, 0);
          aq[q] = __builtin_amdgcn_mfma_f32_16x16x32_bf16(a60, wf4, aq[q], 0, 0, 0);
          aq[q] = __builtin_amdgcn_mfma_f32_16x16x32_bf16(a61, wf5, aq[q], 0, 0, 0);
        }
        float bbA = b0[c], bbB = b0[c + 128], bbC = b0[c + 256];
#pragma unroll
        for (int r = 0; r < 4; ++r) {
          m2[0][r] = aq[0][r] + bbA;
          m2[2][r] = aq[1][r] + bbB;
          m2[6][r] = aq[2][r] + bbC;
        }
      }
      {  // wm2: z0 = row8@W2, z1 = row4@W2 ; K=64, N=256
        f32x4 z0a[2], z1a[2];
#pragma unroll
        for (int q = 0; q < 2; ++q) {
          z0a[q] = (f32x4){0.f, 0.f, 0.f, 0.f};
          z1a[q] = (f32x4){0.f, 0.f, 0.f, 0.f};
        }
        bf16x8 a80 = AF(8, g), a81 = AF(8, 4 + g);
        bf16x8 a40 = AF(4, g), a41 = AF(4, 4 + g);
#pragma unroll
        for (int q = 0; q < 2; ++q) {
          int col = c + q * 128;
          bf16x8 wf0 = *(const bf16x8*)(w2b + ((size_t)((0 * 4 + g) * 256 + col)) * 8);
          bf16x8 wf1 = *(const bf16x8*)(w2b + ((size_t)((1 * 4 + g) * 256 + col)) * 8);
          z0a[q] = __builtin_amdgcn_mfma_f32_16x16x32_bf16(a80, wf0, z0a[q], 0, 0, 0);
          z0a[q] = __builtin_amdgcn_mfma_f32_16x16x32_bf16(a81, wf1, z0a[q], 0, 0, 0);
          z1a[q] = __builtin_amdgcn_mfma_f32_16x16x32_bf16(a40, wf0, z1a[q], 0, 0, 0);
          z1a[q] = __builtin_amdgcn_mfma_f32_16x16x32_bf16(a41, wf1, z1a[q], 0, 0, 0);
        }
#pragma unroll
        for (int r = 0; r < 4; ++r) {
          m2[8][r] = z0a[0][r] - z1a[1][r];
          m2[4][r] = z1a[0][r] + z0a[1][r];
        }
      }
      // epilogue: alpha scale + wigner_inv + atomic scatter
      int h = c >> 4;
#pragma unroll
      for (int r = 0; r < 4; ++r) {
        int e = g * 4 + r;
        float av = alp[e * 8 + h];
        float mm[9];
#pragma unroll
        for (int j = 0; j < 9; ++j) mm[j] = m2[j][r] * av;
        float* np = node + (size_t)tnode[e] * 1152 + c;
#pragma unroll
        for (int i = 0; i < 9; ++i) {
          float s = 0.f;
#pragma unroll
          for (int j = 0; j < 9; ++j) s += wib[e * 81 + i * 9 + j] * mm[j];
          atomicAdd(np + i * 128, s);
        }
      }
    }
#undef AF
  }
}

// ---------------------------------------------------------------------------
// proj_w transpose + per-node projection (unchanged)
// ---------------------------------------------------------------------------
__global__ __launch_bounds__(256) void k_wt(const float* __restrict__ pw, float* __restrict__ wT) {
  int idx = blockIdx.x * 256 + threadIdx.x;
  if (idx >= 3 * 128 * 64) return;
  int l = idx / 8192, r = idx % 8192, i = r / 64, o = r % 64;
  wT[idx] = pw[(l * 64 + o) * 128 + i];
}

__global__ __launch_bounds__(256) void k_proj(const float* __restrict__ node,
                                              const float* __restrict__ wT,
                                              const float* __restrict__ pb,
                                              float* __restrict__ out) {
  __shared__ __align__(16) float A[32 * 132];
  int k = blockIdx.y;
  int n0 = blockIdx.x * 32;
  const int lidx = (k == 0) ? 0 : (k <= 3 ? 1 : 2);
  int tid = threadIdx.x;
  for (int i = tid; i < 32 * 128; i += 256) {
    int nn = i >> 7, ii = i & 127;
    int n = n0 + nn;
    A[nn * 132 + ii] = (n < N_NODES) ? node[((size_t)n * 9 + k) * 128 + ii] : 0.f;
  }
  __syncthreads();
  int o = tid & 63, wid = tid >> 6;
  float acc[8] = {0.f, 0.f, 0.f, 0.f, 0.f, 0.f, 0.f, 0.f};
#pragma unroll 4
  for (int i = 0; i < 128; ++i) {
    float w = wT[lidx * 8192 + i * 64 + o];
#pragma unroll
    for (int r = 0; r < 8; ++r) acc[r] += A[(wid * 8 + r) * 132 + i] * w;
  }
  float bias = (k == 0) ? pb[o] : 0.f;
#pragma unroll
  for (int r = 0; r < 8; ++r) {
    int n = n0 + wid * 8 + r;
    if (n < N_NODES) out[((size_t)n * 9 + k) * 64 + o] = acc[r] + bias;
  }
}

// ---------------------------------------------------------------------------
extern "C" void kernel_launch(void* const* d_in, const int* in_sizes, int n_in,
                              void* d_out, int out_size, void* d_ws, size_t ws_size,
                              hipStream_t stream) {
  const float* x      = (const float*)d_in[0];
  const int*   an     = (const int*)d_in[1];
  const float* edist  = (const float*)d_in[2];
  const int*   eidx   = (const int*)d_in[3];
  const float* t_ij   = (const float*)d_in[4];
  const float* rl_ij  = (const float*)d_in[5];
  const float* wig    = (const float*)d_in[6];
  const float* winv   = (const float*)d_in[7];
  const float* semb   = (const float*)d_in[8];
  const float* temb   = (const float*)d_in[9];
  const float* rw1    = (const float*)d_in[10];
  const float* rb1    = (const float*)d_in[11];
  const float* rlnw   = (const float*)d_in[12];
  const float* rlnb   = (const float*)d_in[13];
  const float* rw2    = (const float*)d_in[14];
  const float* rb2    = (const float*)d_in[15];
  const float* c1w0   = (const float*)d_in[16];
  const float* c1b0   = (const float*)d_in[17];
  // d_in[18], d_in[19]: c1_wm1 / c1_wm2 — dead code in the reference
  const float* lnaw   = (const float*)d_in[20];
  const float* lnab   = (const float*)d_in[21];
  const float* adot   = (const float*)d_in[22];
  const float* gwh    = (const float*)d_in[23];
  const float* gwx    = (const float*)d_in[24];
  const float* gwt    = (const float*)d_in[25];
  const float* c2w0   = (const float*)d_in[26];
  const float* c2b0   = (const float*)d_in[27];
  const float* c2w1   = (const float*)d_in[28];
  const float* c2w2   = (const float*)d_in[29];
  const float* pw     = (const float*)d_in[30];
  const float* pb     = (const float*)d_in[31];
  float* out = (float*)d_out;

  char* p = (char*)d_ws;
  float* ws_attn  = (float*)p; p += (size_t)E_CNT * 320 * 4;
  float* ws_apre  = (float*)p; p += (size_t)E_CNT * 8 * 4;
  float* ws_ex    = (float*)p; p += (size_t)E_CNT * 8 * 4;
  unsigned* segk  = (unsigned*)p; p += (size_t)N_NODES * 8 * 4;
  float* denom    = (float*)p; p += (size_t)N_NODES * 8 * 4;
  float* node     = (float*)p; p += (size_t)N_NODES * 1152 * 4;
  float* wT       = (float*)p; p += (size_t)3 * 128 * 64 * 4;
  __bf16* w0r     = (__bf16*)p; p += (size_t)48 * 576 * 8 * 2;
  __bf16* w0b     = (__bf16*)p; p += (size_t)24 * 384 * 8 * 2;
  __bf16* w1b     = (__bf16*)p; p += (size_t)16 * 512 * 8 * 2;
  __bf16* w2b     = (__bf16*)p; p += (size_t)8 * 256 * 8 * 2;

  hipMemsetAsync(segk, 0, N_NODES * 8 * 4, stream);
  hipMemsetAsync(denom, 0, N_NODES * 8 * 4, stream);
  hipMemsetAsync(node, 0, (size_t)N_NODES * 1152 * 4, stream);

  k_cvt<<<108, 256, 0, stream>>>(c1w0, w0r, 48, 576, 768);
  k_cvt<<<36, 256, 0, stream>>>(c2w0, w0b, 24, 384, 384);
  k_cvt<<<32, 256, 0, stream>>>(c2w1, w1b, 16, 512, 512);
  k_cvt<<<8, 256, 0, stream>>>(c2w2, w2b, 8, 256, 256);
  k_wt<<<96, 256, 0, stream>>>(pw, wT);
  k_phase1<<<E_CNT / 16, 256, 0, stream>>>(x, an, edist, eidx, wig, semb, temb,
                                           rw1, rb1, rlnw, rlnb, rw2, rb2,
                                           w0r, c1b0, lnaw, lnab, adot,
                                           ws_attn, ws_apre);
  k_segmax<<<(E_CNT * 8) / 256, 256, 0, stream>>>(ws_apre, eidx, segk);
  k_expsum<<<(E_CNT * 8) / 256, 256, 0, stream>>>(ws_apre, eidx, segk, ws_ex, denom);
  k_phase2<<<E_CNT / 16, 256, 0, stream>>>(x, eidx, t_ij, rl_ij, winv,
                                           gwh, gwx, gwt, w0b, c2b0, w1b, w2b,
                                           ws_attn, ws_ex, denom, node);
  k_proj<<<dim3((N_NODES + 31) / 32, 9), 256, 0, stream>>>(node, wT, pb, out);
}

// Round 7
// 2090.474 us; speedup vs baseline: 1.0432x; 1.0432x over previous
//
#include <hip/hip_runtime.h>

#define E_CNT 80000
#define N_NODES 10000

typedef __attribute__((ext_vector_type(8))) __bf16 bf16x8;
typedef __attribute__((ext_vector_type(4))) float f32x4;

__device__ __forceinline__ float sigmoidf_(float x) { return 1.f / (1.f + __expf(-x)); }

__device__ __forceinline__ unsigned fkey(float f) {
  unsigned u = __float_as_uint(f);
  return (u & 0x80000000u) ? ~u : (u | 0x80000000u);
}
__device__ __forceinline__ float unfkey(unsigned k) {
  unsigned u = (k & 0x80000000u) ? (k & 0x7FFFFFFFu) : ~k;
  return __uint_as_float(u);
}

// ---------------------------------------------------------------------------
// Generic f32 [K, ld] (first N cols) -> bf16 MFMA-B fragment layout:
// dst[(ksg*N + col)*8 + j] = src[(ksg*8 + j)*ld + col].
// ---------------------------------------------------------------------------
__global__ __launch_bounds__(256) void k_cvt(const float* __restrict__ src,
                                             __bf16* __restrict__ dst,
                                             int K8, int N, int ld) {
  int idx = blockIdx.x * 256 + threadIdx.x;
  if (idx >= K8 * N) return;
  int ksg = idx / N, col = idx % N;
#pragma unroll
  for (int j = 0; j < 8; ++j)
    dst[(size_t)idx * 8 + j] = (__bf16)src[(size_t)(ksg * 8 + j) * ld + col];
}

// w1n: K=256 ([x3,x7,x1,x5]) x N=512 (o*128+c, o -> m2 rows {3,7,1,5}), signs folded.
__global__ __launch_bounds__(256) void k_cvt1(const float* __restrict__ w1,
                                              __bf16* __restrict__ dst) {
  int idx = blockIdx.x * 256 + threadIdx.x;   // 32*512
  if (idx >= 32 * 512) return;
  int ksg = idx >> 9, col = idx & 511;
  int o = col >> 7, c = col & 127;
  const int tc[4] = {0, 128, 256, 384};
  const int bc[4] = {256, 384, 0, 128};
  const float sg[4] = {-1.f, -1.f, 1.f, 1.f};
#pragma unroll
  for (int j = 0; j < 8; ++j) {
    int kk = ksg * 8 + j;
    float v = (kk < 128) ? w1[(size_t)kk * 512 + tc[o] + c]
                         : sg[o] * w1[(size_t)(kk - 128) * 512 + bc[o] + c];
    dst[(size_t)idx * 8 + j] = (__bf16)v;
  }
}

// w2n: K=128 ([x8,x4]) x N=256 (o -> m2 rows {8,4}), signs folded.
__global__ __launch_bounds__(256) void k_cvt2(const float* __restrict__ w2,
                                              __bf16* __restrict__ dst) {
  int idx = blockIdx.x * 256 + threadIdx.x;   // 16*256
  if (idx >= 16 * 256) return;
  int ksg = idx >> 8, col = idx & 255;
  int o = col >> 7, c = col & 127;
#pragma unroll
  for (int j = 0; j < 8; ++j) {
    int kk = ksg * 8 + j;
    float v;
    if (kk < 64) v = w2[(size_t)kk * 256 + (o == 0 ? c : c + 128)];
    else         v = (o == 0) ? -w2[(size_t)(kk - 64) * 256 + c + 128]
                              :  w2[(size_t)(kk - 64) * 256 + c];
    dst[(size_t)idx * 8 + j] = (__bf16)v;
  }
}

// ---------------------------------------------------------------------------
// Phase 1 (unchanged from R5). 16 edges/block, 256 threads, 3 blocks/CU.
// ---------------------------------------------------------------------------
__global__ __launch_bounds__(256, 3) void k_phase1(
    const float* __restrict__ x, const int* __restrict__ an,
    const float* __restrict__ edist, const int* __restrict__ eidx,
    const float* __restrict__ wigner,
    const float* __restrict__ semb, const float* __restrict__ temb,
    const float* __restrict__ rw1, const float* __restrict__ rb1,
    const float* __restrict__ rlnw, const float* __restrict__ rlnb,
    const float* __restrict__ rw2, const float* __restrict__ rb2,
    const __bf16* __restrict__ w0r, const float* __restrict__ b0,
    const float* __restrict__ lnaw, const float* __restrict__ lnab,
    const float* __restrict__ adot,
    float* __restrict__ ws_attn, float* __restrict__ ws_apre)
{
  __shared__ __align__(16) float pool[6160];
  __shared__ __align__(16) float sb[2048];
  __shared__ __align__(16) __bf16 a_lds[6144];   // [ksg=48][e=16][j=8]
  __shared__ float wgs[432];
  __shared__ int sidx[16], tidx[16], ansh[16], anth[16];

  const int tid = threadIdx.x;
  const int e0 = blockIdx.x * 16;

  if (tid < 16) {
    int s = eidx[e0 + tid], t = eidx[E_CNT + e0 + tid];
    sidx[tid] = s; tidx[tid] = t; ansh[tid] = an[s]; anth[tid] = an[t];
  }
  for (int i = tid; i < 432; i += 256) {
    int e = i / 27, r = i % 27, kk = r / 9, j = r % 9;
    int row = (kk == 0) ? 0 : (kk == 1 ? 2 : 6);
    wgs[i] = wigner[(size_t)(e0 + e) * 81 + row * 9 + j];
  }
  __syncthreads();

  float* xe = pool;
  for (int i = tid; i < 16 * 320; i += 256) {
    int e = i / 320, c = i % 320;
    float v;
    if (c < 64)       v = edist[(size_t)(e0 + e) * 64 + c];
    else if (c < 192) v = semb[ansh[e] * 128 + (c - 64)];
    else              v = temb[anth[e] * 128 + (c - 192)];
    xe[e * 320 + c] = v;
  }
  __syncthreads();

  {
    int col = tid & 127, half = tid >> 7;
    float acc[8];
#pragma unroll
    for (int i = 0; i < 8; ++i) acc[i] = 0.f;
#pragma unroll 4
    for (int k = 0; k < 320; ++k) {
      float w = rw1[k * 128 + col];
#pragma unroll
      for (int i = 0; i < 8; ++i) acc[i] += xe[(half * 8 + i) * 320 + k] * w;
    }
    float bb = rb1[col];
#pragma unroll
    for (int i = 0; i < 8; ++i) sb[(half * 8 + i) * 128 + col] = acc[i] + bb;
  }
  __syncthreads();

  {
    int wid = tid >> 6, lane = tid & 63;
    for (int e = wid; e < 16; e += 4) {
      float v0 = sb[e * 128 + lane], v1 = sb[e * 128 + lane + 64];
      float s1 = v0 + v1, s2 = v0 * v0 + v1 * v1;
#pragma unroll
      for (int m = 32; m >= 1; m >>= 1) {
        s1 += __shfl_xor(s1, m);
        s2 += __shfl_xor(s2, m);
      }
      float mu = s1 * (1.f / 128.f);
      float var = s2 * (1.f / 128.f) - mu * mu;
      float rstd = rsqrtf(var + 1e-5f);
      float y0 = (v0 - mu) * rstd * rlnw[lane] + rlnb[lane];
      float y1 = (v1 - mu) * rstd * rlnw[lane + 64] + rlnb[lane + 64];
      sb[e * 128 + lane]      = y0 * sigmoidf_(y0) * (1.f / 0.6f);
      sb[e * 128 + lane + 64] = y1 * sigmoidf_(y1) * (1.f / 0.6f);
    }
  }
  __syncthreads();

  float* rbuf = pool;
  {
    int col128 = tid & 127, half = tid >> 7;
    for (int cc = 0; cc < 3; ++cc) {
      int col = cc * 128 + col128;
      float acc[8];
#pragma unroll
      for (int i = 0; i < 8; ++i) acc[i] = 0.f;
#pragma unroll 4
      for (int k = 0; k < 128; ++k) {
        float w = rw2[k * 768 + col];
#pragma unroll
        for (int i = 0; i < 8; ++i) acc[i] += sb[(half * 8 + i) * 128 + k] * w;
      }
      float bb = rb2[col];
#pragma unroll
      for (int i = 0; i < 8; ++i) rbuf[(half * 8 + i) * 385 + col] = acc[i] + bb;
    }
  }
  __syncthreads();

  {
    int e = tid & 15, cg = tid >> 4;
    int c0 = cg * 8;
    const float* xb = (c0 < 64) ? (x + (size_t)sidx[e] * 576 + c0)
                                : (x + (size_t)tidx[e] * 576 + (c0 - 64));
    float xc[9][8];
#pragma unroll
    for (int j = 0; j < 9; ++j) {
      float4 u0 = *(const float4*)(xb + j * 64);
      float4 u1 = *(const float4*)(xb + j * 64 + 4);
      xc[j][0] = u0.x; xc[j][1] = u0.y; xc[j][2] = u0.z; xc[j][3] = u0.w;
      xc[j][4] = u1.x; xc[j][5] = u1.y; xc[j][6] = u1.z; xc[j][7] = u1.w;
    }
#pragma unroll
    for (int kk = 0; kk < 3; ++kk) {
      float wv[9];
#pragma unroll
      for (int j = 0; j < 9; ++j) wv[j] = wgs[e * 27 + kk * 9 + j];
      __bf16* ap = a_lds + ((kk * 16 + cg) * 16 + e) * 8;
#pragma unroll
      for (int cu = 0; cu < 8; ++cu) {
        float m = 0.f;
#pragma unroll
        for (int j = 0; j < 9; ++j) m += wv[j] * xc[j][cu];
        int colc = kk * 128 + c0 + cu;
        ap[cu] = (__bf16)(m * rbuf[e * 385 + colc]);
      }
    }
  }
  __syncthreads();

  float* sb5 = pool;
  {
    int lane = tid & 63, wv = tid >> 6;
    int erow = lane & 15, g = lane >> 4;
    bf16x8 af[12];
#pragma unroll
    for (int ks = 0; ks < 12; ++ks)
      af[ks] = *(const bf16x8*)(a_lds + ((ks * 4 + g) * 16 + erow) * 8);
    for (int tt = 0; tt < 9; ++tt) {
      int tile = wv * 9 + tt;
      int col = tile * 16 + erow;
      f32x4 acc = {0.f, 0.f, 0.f, 0.f};
#pragma unroll
      for (int ks = 0; ks < 12; ++ks) {
        bf16x8 bf = *(const bf16x8*)(w0r + ((size_t)((ks * 4 + g) * 576) + col) * 8);
        acc = __builtin_amdgcn_mfma_f32_16x16x32_bf16(af[ks], bf, acc, 0, 0, 0);
      }
      if (tile < 16) {
#pragma unroll
        for (int r = 0; r < 4; ++r) sb5[(g * 4 + r) * 260 + col] = acc[r];
      } else {
        float bb = b0[col];
#pragma unroll
        for (int r = 0; r < 4; ++r)
          ws_attn[(size_t)(e0 + g * 4 + r) * 320 + (col - 256)] = acc[r] + bb;
      }
    }
  }
  __syncthreads();

  {
    float bb = b0[tid];
    int h = tid >> 5, kk = tid & 31;
    float lw = lnaw[kk], lb = lnab[kk], ad = adot[h * 32 + kk];
#pragma unroll
    for (int e = 0; e < 16; ++e) {
      float v = sb5[e * 260 + tid] + bb;
      float s1 = v, s2 = v * v;
#pragma unroll
      for (int m = 16; m >= 1; m >>= 1) {
        s1 += __shfl_xor(s1, m);
        s2 += __shfl_xor(s2, m);
      }
      float mu = s1 * (1.f / 32.f);
      float var = s2 * (1.f / 32.f) - mu * mu;
      float rstd = rsqrtf(var + 1e-5f);
      float xn = (v - mu) * rstd * lw + lb;
      float sl = 0.6f * xn + 0.4f * xn * (2.f * sigmoidf_(xn) - 1.f);
      float p = sl * ad;
#pragma unroll
      for (int m = 16; m >= 1; m >>= 1) p += __shfl_xor(p, m);
      if (kk == 0) ws_apre[(size_t)(e0 + e) * 8 + h] = p;
    }
  }
}

// ---------------------------------------------------------------------------
// segment max / exp-sum
// ---------------------------------------------------------------------------
__global__ __launch_bounds__(256) void k_segmax(const float* __restrict__ apre,
                                                const int* __restrict__ eidx,
                                                unsigned* __restrict__ segk) {
  int idx = blockIdx.x * 256 + threadIdx.x;
  if (idx >= E_CNT * 8) return;
  int e = idx >> 3, h = idx & 7;
  int t = eidx[E_CNT + e];
  atomicMax(&segk[t * 8 + h], fkey(apre[idx]));
}

__global__ __launch_bounds__(256) void k_expsum(const float* __restrict__ apre,
                                                const int* __restrict__ eidx,
                                                const unsigned* __restrict__ segk,
                                                float* __restrict__ ex_out,
                                                float* __restrict__ denom) {
  int idx = blockIdx.x * 256 + threadIdx.x;
  if (idx >= E_CNT * 8) return;
  int e = idx >> 3, h = idx & 7;
  int t = eidx[E_CNT + e];
  float m = unfkey(segk[t * 8 + h]);
  float ex = __expf(apre[idx] - m);
  ex_out[idx] = ex;
  atomicAdd(&denom[t * 8 + h], ex);
}

// ---------------------------------------------------------------------------
// Phase 2: gates (f32, staged back into xs) -> vector convert to bf16 A-frags
// -> conv2 as 9 single-accumulator MFMA chains (signs folded into w1n/w2n)
// -> alpha*wigner_inv + atomic scatter. 16 edges/block, 2 blocks/CU.
// ---------------------------------------------------------------------------
__global__ __launch_bounds__(256, 2) void k_phase2(
    const float* __restrict__ x, const int* __restrict__ eidx,
    const float* __restrict__ t_ij, const float* __restrict__ rl_ij,
    const float* __restrict__ winv,
    const float* __restrict__ gwh, const float* __restrict__ gwx, const float* __restrict__ gwt,
    const __bf16* __restrict__ w0b, const float* __restrict__ b0,
    const __bf16* __restrict__ w1n, const __bf16* __restrict__ w2n,
    const float* __restrict__ ws_attn, const float* __restrict__ ws_ex,
    const float* __restrict__ denom,
    float* __restrict__ node)
{
  __shared__ __align__(16) float xs[16 * 576];
  __shared__ __align__(16) __bf16 mb[9 * 8 * 16 * 8];   // [row][ksg][e][j]
  __shared__ float wib[16 * 81];
  __shared__ float alp[128];
  __shared__ float rlb[128];
  __shared__ float malp[16];
  __shared__ int tnode[16];

  const int tid = threadIdx.x;
  const int e0 = blockIdx.x * 16;

  if (tid < 16) tnode[tid] = eidx[E_CNT + e0 + tid];
  __syncthreads();

  if (tid < 128) {
    int e = tid >> 3, h = tid & 7;
    float ex = ws_ex[(size_t)(e0 + e) * 8 + h];
    alp[tid] = ex / (denom[tnode[e] * 8 + h] + 1e-16f);
  } else {
    int i = tid - 128;
    int e = i >> 3;
    rlb[i] = rl_ij[(size_t)(e0 + e) * 8 + (i & 7)];
  }
  for (int i = tid; i < 16 * 81; i += 256) {
    int e = i / 81, r = i % 81;
    wib[i] = winv[(size_t)(e0 + e) * 81 + r];
  }
  for (int i = tid; i < 16 * 576; i += 256) {
    int e = i / 576, c = i % 576;
    xs[i] = x[(size_t)tnode[e] * 576 + c];
  }
  __syncthreads();
  if (tid < 16) {
    float s = 0.f;
#pragma unroll
    for (int h = 0; h < 8; ++h) s += alp[tid * 8 + h];
    malp[tid] = s * 0.125f;
  }
  __syncthreads();

  // gates: f32 VALU, results staged back into xs (dead after reads)
  {
    int d = tid & 63, wid = tid >> 6;
    float acch[4] = {0.f, 0.f, 0.f, 0.f}, acct[4] = {0.f, 0.f, 0.f, 0.f};
#pragma unroll 4
    for (int k = 0; k < 64; ++k) {
      float w = gwh[k * 64 + d];
#pragma unroll
      for (int i = 0; i < 4; ++i) acch[i] += xs[(wid * 4 + i) * 576 + k] * w;
    }
#pragma unroll 4
    for (int k = 0; k < 128; ++k) {
      float w = gwt[k * 64 + d];
#pragma unroll
      for (int i = 0; i < 4; ++i) acct[i] += t_ij[(size_t)(e0 + wid * 4 + i) * 128 + k] * w;
    }
    float xp[4][8];
#pragma unroll
    for (int i = 0; i < 4; ++i)
#pragma unroll
      for (int k8 = 0; k8 < 8; ++k8) xp[i][k8] = 0.f;
#pragma unroll 2
    for (int c = 0; c < 64; ++c) {
      float w = gwx[c * 64 + d];
#pragma unroll
      for (int i = 0; i < 4; ++i) {
#pragma unroll
        for (int k8 = 0; k8 < 8; ++k8)
          xp[i][k8] += xs[(wid * 4 + i) * 576 + (k8 + 1) * 64 + c] * w;
      }
    }
    __syncthreads();   // all reads of staged x[tgt] complete before overwrite
#pragma unroll
    for (int i = 0; i < 4; ++i) {
      int e = wid * 4 + i;
      float ml = malp[e];
      const float* wsb = ws_attn + (size_t)(e0 + e) * 320;
      float hv = acch[i]; hv = hv * sigmoidf_(hv);
      float tv = acct[i]; tv = tv * sigmoidf_(tv);
      float os  = wsb[d] * ml;
      float od0 = wsb[64 + d] * ml,  od1 = wsb[128 + d] * ml;
      float ot0 = wsb[192 + d] * ml, ot1 = wsb[256 + d] * ml;
      xs[e * 576 + d] = os * hv;
#pragma unroll
      for (int j = 0; j < 3; ++j)
        xs[e * 576 + (1 + j) * 64 + d] = od0 * xp[i][j] + ot0 * tv * rlb[e * 8 + j];
#pragma unroll
      for (int j = 0; j < 5; ++j)
        xs[e * 576 + (4 + j) * 64 + d] = od1 * xp[i][3 + j] + ot1 * tv * rlb[e * 8 + 3 + j];
    }
  }
  __syncthreads();

  // vector convert xs -> mb (bf16 A-fragment layout, 16B writes)
  for (int i = tid; i < 1152; i += 256) {
    int row = i >> 7;
    int rem = i & 127;
    int ksg = rem >> 4, e = rem & 15;
    const float* sp = xs + e * 576 + row * 64 + ksg * 8;
    float4 u0 = *(const float4*)sp;
    float4 u1 = *(const float4*)(sp + 4);
    bf16x8 v;
    v[0] = (__bf16)u0.x; v[1] = (__bf16)u0.y; v[2] = (__bf16)u0.z; v[3] = (__bf16)u0.w;
    v[4] = (__bf16)u1.x; v[5] = (__bf16)u1.y; v[6] = (__bf16)u1.z; v[7] = (__bf16)u1.w;
    *(bf16x8*)(mb + (size_t)i * 8) = v;
  }
  __syncthreads();

  // conv2: 9 single-accumulator MFMA chains per (wave, gi)
  {
    const int lane = tid & 63, wv = tid >> 6;
    const int e16 = lane & 15, g = lane >> 4;
#define AF(row, ks) (*(const bf16x8*)(mb + (((row) * 8 + (ks)) * 16 + e16) * 8))
#pragma unroll 1
    for (int gi = 0; gi < 2; ++gi) {
      const int c = (wv * 2 + gi) * 16 + e16;   // channel 0..127
      f32x4 m2v[9];
      {  // wm0: rows {0,2,6}, K=192 -> m2 rows {0,2,6} (+bias)
        const int rws[3] = {0, 2, 6};
#pragma unroll
        for (int o = 0; o < 3; ++o) {
          f32x4 acc = {0.f, 0.f, 0.f, 0.f};
#pragma unroll
          for (int m = 0; m < 6; ++m) {
            bf16x8 bfr = *(const bf16x8*)(w0b + ((size_t)((m * 4 + g) * 384) + o * 128 + c) * 8);
            acc = __builtin_amdgcn_mfma_f32_16x16x32_bf16(AF(rws[m >> 1], (m & 1) * 4 + g), bfr, acc, 0, 0, 0);
          }
          float bb = b0[o * 128 + c];
          acc[0] += bb; acc[1] += bb; acc[2] += bb; acc[3] += bb;
          m2v[rws[o]] = acc;
        }
      }
      {  // wm1: A=[x3,x7,x1,x5] K=256, w1n signs folded -> m2 rows {3,7,1,5}
        const int rws[4] = {3, 7, 1, 5};
#pragma unroll
        for (int o = 0; o < 4; ++o) {
          f32x4 acc = {0.f, 0.f, 0.f, 0.f};
#pragma unroll
          for (int m = 0; m < 8; ++m) {
            bf16x8 bfr = *(const bf16x8*)(w1n + ((size_t)((m * 4 + g) * 512) + o * 128 + c) * 8);
            acc = __builtin_amdgcn_mfma_f32_16x16x32_bf16(AF(rws[m >> 1], (m & 1) * 4 + g), bfr, acc, 0, 0, 0);
          }
          m2v[rws[o]] = acc;
        }
      }
      {  // wm2: A=[x8,x4] K=128, w2n signs folded -> m2 rows {8,4}
        const int rws[2] = {8, 4};
#pragma unroll
        for (int o = 0; o < 2; ++o) {
          f32x4 acc = {0.f, 0.f, 0.f, 0.f};
#pragma unroll
          for (int m = 0; m < 4; ++m) {
            bf16x8 bfr = *(const bf16x8*)(w2n + ((size_t)((m * 4 + g) * 256) + o * 128 + c) * 8);
            acc = __builtin_amdgcn_mfma_f32_16x16x32_bf16(AF(rws[m >> 1], (m & 1) * 4 + g), bfr, acc, 0, 0, 0);
          }
          m2v[rws[o]] = acc;
        }
      }
      // epilogue: alpha scale + wigner_inv + atomic scatter
      int h = c >> 4;
#pragma unroll
      for (int r = 0; r < 4; ++r) {
        int e = g * 4 + r;
        float av = alp[e * 8 + h];
        float mm[9];
#pragma unroll
        for (int j = 0; j < 9; ++j) mm[j] = m2v[j][r] * av;
        float* np = node + (size_t)tnode[e] * 1152 + c;
#pragma unroll
        for (int i = 0; i < 9; ++i) {
          float s = 0.f;
#pragma unroll
          for (int j = 0; j < 9; ++j) s += wib[e * 81 + i * 9 + j] * mm[j];
          atomicAdd(np + i * 128, s);
        }
      }
    }
#undef AF
  }
}

// ---------------------------------------------------------------------------
// proj_w transpose + per-node projection (unchanged)
// ---------------------------------------------------------------------------
__global__ __launch_bounds__(256) void k_wt(const float* __restrict__ pw, float* __restrict__ wT) {
  int idx = blockIdx.x * 256 + threadIdx.x;
  if (idx >= 3 * 128 * 64) return;
  int l = idx / 8192, r = idx % 8192, i = r / 64, o = r % 64;
  wT[idx] = pw[(l * 64 + o) * 128 + i];
}

__global__ __launch_bounds__(256) void k_proj(const float* __restrict__ node,
                                              const float* __restrict__ wT,
                                              const float* __restrict__ pb,
                                              float* __restrict__ out) {
  __shared__ __align__(16) float A[32 * 132];
  int k = blockIdx.y;
  int n0 = blockIdx.x * 32;
  const int lidx = (k == 0) ? 0 : (k <= 3 ? 1 : 2);
  int tid = threadIdx.x;
  for (int i = tid; i < 32 * 128; i += 256) {
    int nn = i >> 7, ii = i & 127;
    int n = n0 + nn;
    A[nn * 132 + ii] = (n < N_NODES) ? node[((size_t)n * 9 + k) * 128 + ii] : 0.f;
  }
  __syncthreads();
  int o = tid & 63, wid = tid >> 6;
  float acc[8] = {0.f, 0.f, 0.f, 0.f, 0.f, 0.f, 0.f, 0.f};
#pragma unroll 4
  for (int i = 0; i < 128; ++i) {
    float w = wT[lidx * 8192 + i * 64 + o];
#pragma unroll
    for (int r = 0; r < 8; ++r) acc[r] += A[(wid * 8 + r) * 132 + i] * w;
  }
  float bias = (k == 0) ? pb[o] : 0.f;
#pragma unroll
  for (int r = 0; r < 8; ++r) {
    int n = n0 + wid * 8 + r;
    if (n < N_NODES) out[((size_t)n * 9 + k) * 64 + o] = acc[r] + bias;
  }
}

// ---------------------------------------------------------------------------
extern "C" void kernel_launch(void* const* d_in, const int* in_sizes, int n_in,
                              void* d_out, int out_size, void* d_ws, size_t ws_size,
                              hipStream_t stream) {
  const float* x      = (const float*)d_in[0];
  const int*   an     = (const int*)d_in[1];
  const float* edist  = (const float*)d_in[2];
  const int*   eidx   = (const int*)d_in[3];
  const float* t_ij   = (const float*)d_in[4];
  const float* rl_ij  = (const float*)d_in[5];
  const float* wig    = (const float*)d_in[6];
  const float* winv   = (const float*)d_in[7];
  const float* semb   = (const float*)d_in[8];
  const float* temb   = (const float*)d_in[9];
  const float* rw1    = (const float*)d_in[10];
  const float* rb1    = (const float*)d_in[11];
  const float* rlnw   = (const float*)d_in[12];
  const float* rlnb   = (const float*)d_in[13];
  const float* rw2    = (const float*)d_in[14];
  const float* rb2    = (const float*)d_in[15];
  const float* c1w0   = (const float*)d_in[16];
  const float* c1b0   = (const float*)d_in[17];
  // d_in[18], d_in[19]: c1_wm1 / c1_wm2 — dead code in the reference
  const float* lnaw   = (const float*)d_in[20];
  const float* lnab   = (const float*)d_in[21];
  const float* adot   = (const float*)d_in[22];
  const float* gwh    = (const float*)d_in[23];
  const float* gwx    = (const float*)d_in[24];
  const float* gwt    = (const float*)d_in[25];
  const float* c2w0   = (const float*)d_in[26];
  const float* c2b0   = (const float*)d_in[27];
  const float* c2w1   = (const float*)d_in[28];
  const float* c2w2   = (const float*)d_in[29];
  const float* pw     = (const float*)d_in[30];
  const float* pb     = (const float*)d_in[31];
  float* out = (float*)d_out;

  char* p = (char*)d_ws;
  float* ws_attn  = (float*)p; p += (size_t)E_CNT * 320 * 4;
  float* ws_apre  = (float*)p; p += (size_t)E_CNT * 8 * 4;
  float* ws_ex    = (float*)p; p += (size_t)E_CNT * 8 * 4;
  unsigned* segk  = (unsigned*)p; p += (size_t)N_NODES * 8 * 4;
  float* denom    = (float*)p; p += (size_t)N_NODES * 8 * 4;
  float* node     = (float*)p; p += (size_t)N_NODES * 1152 * 4;
  float* wT       = (float*)p; p += (size_t)3 * 128 * 64 * 4;
  __bf16* w0r     = (__bf16*)p; p += (size_t)48 * 576 * 8 * 2;
  __bf16* w0b     = (__bf16*)p; p += (size_t)24 * 384 * 8 * 2;
  __bf16* w1n     = (__bf16*)p; p += (size_t)32 * 512 * 8 * 2;
  __bf16* w2n     = (__bf16*)p; p += (size_t)16 * 256 * 8 * 2;

  hipMemsetAsync(segk, 0, N_NODES * 8 * 4, stream);
  hipMemsetAsync(denom, 0, N_NODES * 8 * 4, stream);
  hipMemsetAsync(node, 0, (size_t)N_NODES * 1152 * 4, stream);

  k_cvt<<<108, 256, 0, stream>>>(c1w0, w0r, 48, 576, 768);
  k_cvt<<<36, 256, 0, stream>>>(c2w0, w0b, 24, 384, 384);
  k_cvt1<<<64, 256, 0, stream>>>(c2w1, w1n);
  k_cvt2<<<16, 256, 0, stream>>>(c2w2, w2n);
  k_wt<<<96, 256, 0, stream>>>(pw, wT);
  k_phase1<<<E_CNT / 16, 256, 0, stream>>>(x, an, edist, eidx, wig, semb, temb,
                                           rw1, rb1, rlnw, rlnb, rw2, rb2,
                                           w0r, c1b0, lnaw, lnab, adot,
                                           ws_attn, ws_apre);
  k_segmax<<<(E_CNT * 8) / 256, 256, 0, stream>>>(ws_apre, eidx, segk);
  k_expsum<<<(E_CNT * 8) / 256, 256, 0, stream>>>(ws_apre, eidx, segk, ws_ex, denom);
  k_phase2<<<E_CNT / 16, 256, 0, stream>>>(x, eidx, t_ij, rl_ij, winv,
                                           gwh, gwx, gwt, w0b, c2b0, w1n, w2n,
                                           ws_attn, ws_ex, denom, node);
  k_proj<<<dim3((N_NODES + 31) / 32, 9), 256, 0, stream>>>(node, wT, pb, out);
}